// Round 6
// baseline (459.901 us; speedup 1.0000x reference)
//
#include <hip/hip_runtime.h>

// 2-layer LSTM, B=1024 T=512 D=1 H=64. 256 blocks x 512 threads (all 256 CUs).
// MB=4 batches/block. Waves 0-3 = layer0 step t; waves 4-7 = layer1 step t-1.
// Chain-optimized: x fully preloaded to LDS; L1 uses 4 parallel MFMA accs +
// add tree; gate-g shuffled/activated first (longest trans chain starts early);
// unroll-2 with compile-time parities; 1 barrier/step.

typedef _Float16 f16x8 __attribute__((ext_vector_type(8)));
typedef float f32x4 __attribute__((ext_vector_type(4)));

#define TSTEPS 512
#define MB 4
#define L2E 1.44269504088896340736f

__device__ __forceinline__ int hidx(int row, int j) {
    // swizzled index into a 16x64 half tile
    return row * 64 + ((((j >> 3) ^ (row & 7)) << 3) | (j & 7));
}

__global__ __launch_bounds__(512) void lstm2_kernel(
    const float* __restrict__ x,
    const float* __restrict__ W_ih0, const float* __restrict__ W_hh0,
    const float* __restrict__ b_ih0, const float* __restrict__ b_hh0,
    const float* __restrict__ W_ih1, const float* __restrict__ W_hh1,
    const float* __restrict__ b_ih1, const float* __restrict__ b_hh1,
    const float* __restrict__ W_fc,  const float* __restrict__ b_fc,
    float* __restrict__ out)
{
    __shared__ __align__(16) _Float16 h0s[2][16 * 64];
    __shared__ __align__(16) _Float16 h1s[2][16 * 64];
    __shared__ __align__(16) float    xlds[TSTEPS * 4];   // [t][batch 0..3]

    const int tid  = (int)threadIdx.x;
    const int lane = tid & 63;
    const int w8   = tid >> 6;          // wave 0..7
    const bool gB  = (w8 >= 4);         // group B = layer1
    const int w    = w8 & 3;            // wave within group
    const int c    = lane & 15;
    const int quad = lane >> 4;
    const int j    = (w << 4) | c;      // hidden unit owned by this lane
    const int b0   = (int)blockIdx.x * MB;

    const int rdA0 = hidx(c, quad * 8);
    const int rdA1 = hidx(c, quad * 8 + 32);
    const int wrH  = hidx(quad, j);     // (batch=quad, unit=j)

    // ---- per-group register weight fragments ----
    float biasc[4], wih0c[4];
    f16x8 bf[4][4];   // A: [g][0..1] = W_hh0 ; B: [g][0..3] = [W_ih1 | W_hh1]

    if (!gB) {
#pragma unroll
        for (int g = 0; g < 4; ++g) {
            const int n = j + 64 * g;
            const float sg = (g == 2) ? (2.0f * L2E) : (-L2E);
            biasc[g] = sg * (b_ih0[n] + b_hh0[n]);
            wih0c[g] = sg * W_ih0[n];                 // D == 1
#pragma unroll
            for (int kb = 0; kb < 2; ++kb) {
                const float* p = W_hh0 + n * 64 + kb * 32 + quad * 8;
#pragma unroll
                for (int q = 0; q < 8; ++q) bf[g][kb][q] = (_Float16)(p[q] * sg);
            }
        }
    } else {
#pragma unroll
        for (int g = 0; g < 4; ++g) {
            const int n = j + 64 * g;
            const float sg = (g == 2) ? (2.0f * L2E) : (-L2E);
            biasc[g] = sg * (b_ih1[n] + b_hh1[n]);
#pragma unroll
            for (int kb = 0; kb < 4; ++kb) {
                const int kk = kb * 32 + quad * 8;
                const float* p = (kk < 64) ? (W_ih1 + n * 64 + kk)
                                           : (W_hh1 + n * 64 + (kk - 64));
#pragma unroll
                for (int q = 0; q < 8; ++q) bf[g][kb][q] = (_Float16)(p[q] * sg);
            }
        }
    }

    // ---- preload ALL of x for this block's 4 batches (8 KB) ----
    {
        const int m  = tid >> 7;            // 0..3
        const int i0 = (tid & 127) * 4;     // 0..508
        const f32x4 v = *(const f32x4*)(x + (size_t)(b0 + m) * TSTEPS + i0);
        xlds[(i0 + 0) * 4 + m] = v[0];
        xlds[(i0 + 1) * 4 + m] = v[1];
        xlds[(i0 + 2) * 4 + m] = v[2];
        xlds[(i0 + 3) * 4 + m] = v[3];
    }
    // zero-init h buffers (rows 4-15 stay zero forever)
    for (int i = tid; i < 16 * 64; i += 512) {
        h0s[0][i] = (_Float16)0.f; h0s[1][i] = (_Float16)0.f;
        h1s[0][i] = (_Float16)0.f; h1s[1][i] = (_Float16)0.f;
    }

    float cst = 0.f;           // cell state for (batch=quad, unit=j)
    const f32x4 zf4 = {0.f, 0.f, 0.f, 0.f};

    // gate extract: lane(c,quad) <- element[quad] of lane c's frag
    auto gsel = [&](const f32x4 a) -> float {
        const float t0 = __shfl(a[0], c, 64);
        const float t1 = __shfl(a[1], c, 64);
        const float t2 = __shfl(a[2], c, 64);
        const float t3 = __shfl(a[3], c, 64);
        return (quad < 2) ? (quad == 0 ? t0 : t1) : (quad == 2 ? t2 : t3);
    };

    // pointwise from 4 gate-frag sums; g-gate first (longest chain)
    auto pointwise = [&](const f32x4 aI, const f32x4 aF, const f32x4 aG,
                         const f32x4 aO) -> float {
        const float ag = gsel(aG);
        const float r_ = __builtin_amdgcn_exp2f(ag);
        const float ai = gsel(aI);
        const float p  = __builtin_amdgcn_exp2f(ai);
        const float af = gsel(aF);
        const float s_ = __builtin_amdgcn_exp2f(af);
        const float ao = gsel(aO);
        const float v  = __builtin_amdgcn_exp2f(ao);
        const float ig = (r_ - 1.f) * __builtin_amdgcn_rcpf((1.f + p) * (1.f + r_));
        const float f  = __builtin_amdgcn_rcpf(1.f + s_);
        const float cc = __builtin_fmaf(f, cst, ig);
        cst = cc;
        const float wv = __builtin_amdgcn_exp2f(cc * (2.f * L2E));
        return (wv - 1.f) * __builtin_amdgcn_rcpf((1.f + v) * (1.f + wv));
    };

    auto stepA = [&](int t, int pr, int pw) {
        const f32x4 xv = *(const f32x4*)&xlds[t * 4];     // broadcast read
        f32x4 accP[4], accQ[4];
#pragma unroll
        for (int g = 0; g < 4; ++g)
#pragma unroll
            for (int r = 0; r < 4; ++r) accP[g][r] = biasc[g] + xv[r] * wih0c[g];
        const f16x8 a0 = *(const f16x8*)&h0s[pr][rdA0];
        const f16x8 a1 = *(const f16x8*)&h0s[pr][rdA1];
#pragma unroll
        for (int g = 0; g < 4; ++g) {
            accP[g] = __builtin_amdgcn_mfma_f32_16x16x32_f16(a0, bf[g][0], accP[g], 0, 0, 0);
            accQ[g] = __builtin_amdgcn_mfma_f32_16x16x32_f16(a1, bf[g][1], zf4,     0, 0, 0);
        }
        const float hv = pointwise(accP[0] + accQ[0], accP[1] + accQ[1],
                                   accP[2] + accQ[2], accP[3] + accQ[3]);
        h0s[pw][wrH] = (_Float16)hv;
    };

    auto stepB = [&](int s, int prh0, int prh1, int pwh1) {
        const f16x8 a10 = *(const f16x8*)&h0s[prh0][rdA0];
        const f16x8 a11 = *(const f16x8*)&h0s[prh0][rdA1];
        const f16x8 a12 = *(const f16x8*)&h1s[prh1][rdA0];
        const f16x8 a13 = *(const f16x8*)&h1s[prh1][rdA1];
        f32x4 accP[4], accQ[4], accR[4], accS[4];
#pragma unroll
        for (int g = 0; g < 4; ++g) {
            f32x4 cb;
#pragma unroll
            for (int r = 0; r < 4; ++r) cb[r] = biasc[g];
            accP[g] = __builtin_amdgcn_mfma_f32_16x16x32_f16(a10, bf[g][0], cb,  0, 0, 0);
            accQ[g] = __builtin_amdgcn_mfma_f32_16x16x32_f16(a11, bf[g][1], zf4, 0, 0, 0);
            accR[g] = __builtin_amdgcn_mfma_f32_16x16x32_f16(a12, bf[g][2], zf4, 0, 0, 0);
            accS[g] = __builtin_amdgcn_mfma_f32_16x16x32_f16(a13, bf[g][3], zf4, 0, 0, 0);
        }
        const float hv = pointwise((accP[0] + accQ[0]) + (accR[0] + accS[0]),
                                   (accP[1] + accQ[1]) + (accR[1] + accS[1]),
                                   (accP[2] + accQ[2]) + (accR[2] + accS[2]),
                                   (accP[3] + accQ[3]) + (accR[3] + accS[3]));
        h1s[pwh1][wrH] = (_Float16)hv;
    };

    __syncthreads();                 // x preload + h init visible
    if (!gB) stepA(0, 1, 0);
    __syncthreads();

    for (int t = 1; t < 511; t += 2) {
        if (!gB) stepA(t, 0, 1); else stepB(t - 1, 0, 1, 0);
        __syncthreads();
        if (!gB) stepA(t + 1, 1, 0); else stepB(t, 1, 0, 1);
        __syncthreads();
    }
    // t = 511
    if (!gB) stepA(511, 0, 1); else stepB(510, 0, 1, 0);
    __syncthreads();
    if (gB) stepB(511, 1, 0, 1);
    __syncthreads();

    // ---- epilogue: h0(511), h1(511) both in parity 1 ----
    if (tid < 8) {
        const int which = tid >> 2, m = tid & 3;
        const _Float16* hb = which ? &h1s[1][0] : &h0s[1][0];
        float s = b_fc[0];
        for (int jj = 0; jj < 64; ++jj) s += (float)hb[hidx(m, jj)] * W_fc[jj];
        out[which * 1024 + b0 + m] = s;
    }
}

extern "C" void kernel_launch(void* const* d_in, const int* in_sizes, int n_in,
                              void* d_out, int out_size, void* d_ws, size_t ws_size,
                              hipStream_t stream) {
    (void)in_sizes; (void)n_in; (void)d_ws; (void)ws_size; (void)out_size;
    lstm2_kernel<<<256, 512, 0, stream>>>(
        (const float*)d_in[0],
        (const float*)d_in[1], (const float*)d_in[2],
        (const float*)d_in[3], (const float*)d_in[4],
        (const float*)d_in[5], (const float*)d_in[6],
        (const float*)d_in[7], (const float*)d_in[8],
        (const float*)d_in[9], (const float*)d_in[10],
        (float*)d_out);
}